// Round 1
// 218.529 us; speedup vs baseline: 1.0305x; 1.0305x over previous
//
#include <hip/hip_runtime.h>
#include <hip/hip_bf16.h>

// Problem constants
#define C_   32
#define S_   20
#define V_   8000     // 20^3
#define K3_  125
#define OC_  375      // 3*K3
#define NP_  384      // padded N
#define KK_  4000     // 32*125

// Workspace layout (float offsets). Peak 2.704M floats = 10.82 MB.
#define WS_ATTN1T 0                        // fp32 [v][c]          256000
#define WS_XTB    256000                   // bf16 [v][c]          128000 fl
#define WS_WDWT   384000                   // fp32 [k][c]            4000
#define WS_WSPT   388000                   // fp32 [k][c]           10976
#define WS_WPWT   398976                   // fp32 [c][o]            1024
#define WS_OFFB   400000                   // bf16 [v][384]       1536000 fl
#define WS_BPREP  1936000                  // bf16 [n][k] 768000 fl; dead after
#define WS_ATTN2T 1936000                  //   gemm -> reused as fp32 [v][c]
// Zero page: first 16 floats of ATTN1T region (dead until deform_kernel,
// which runs after gemm). Zeroed by transpose_kernel.
#define WS_ZERO   WS_ATTN1T

typedef __attribute__((ext_vector_type(8))) short bf16x8;
typedef __attribute__((ext_vector_type(4))) float f32x4;

static __device__ __forceinline__ unsigned short f2bf(float f) {
    union { float f; unsigned u; } v; v.f = f;
    unsigned r = v.u + 0x7FFFu + ((v.u >> 16) & 1u);   // RTNE
    return (unsigned short)(r >> 16);
}
static __device__ __forceinline__ float bf2f(unsigned short b) {
    union { unsigned u; float f; } v; v.u = ((unsigned)b) << 16; return v.f;
}
static __device__ __forceinline__ float asf(unsigned u) {
    union { unsigned u; float f; } v; v.u = u; return v.f;
}

// ---------------------------------------------------------------------------
// Transposes: xtb[v][c] bf16; wdwT[k][c]; wspT[k][c]; wpwT[c][o] (fp32).
// Also zeroes the 64B zero page used by gemm's OOB lane redirect.
// ---------------------------------------------------------------------------
__global__ __launch_bounds__(256) void transpose_kernel(
    const float* __restrict__ x,
    const float* __restrict__ w_dw,
    const float* __restrict__ w_sp,
    const float* __restrict__ w_pw,
    unsigned short* __restrict__ xtb,
    float* __restrict__ wdwT,
    float* __restrict__ wspT,
    float* __restrict__ wpwT,
    float* __restrict__ zpage)
{
    int i = blockIdx.x * 256 + threadIdx.x;
    if (i < 256000) {
        int v = i >> 5, c = i & 31;
        xtb[i] = f2bf(x[c * V_ + v]);
        return;
    }
    int j = i - 256000;
    if (j < 4000)  { wdwT[j] = w_dw[(j & 31) * K3_ + (j >> 5)]; return; }
    j -= 4000;
    if (j < 10976) { wspT[j] = w_sp[(j & 31) * 343 + (j >> 5)]; return; }
    j -= 10976;
    if (j < 1024)  { wpwT[j] = w_pw[(j & 31) * 32 + (j >> 5)]; return; }
    j -= 1024;
    if (j < 16)    { zpage[j] = 0.f; return; }
}

// ---------------------------------------------------------------------------
// Weight transform: Bprep[n][k] bf16, k = tap*32 + c; n >= 375 zeroed.
// ---------------------------------------------------------------------------
__global__ __launch_bounds__(256) void prep_b_kernel(
    const float* __restrict__ w_off, unsigned short* __restrict__ Bprep)
{
    int idx = blockIdx.x * 256 + threadIdx.x;
    if (idx >= NP_ * KK_) return;
    int n = idx / KK_, r = idx % KK_;
    int tap = r >> 5, c = r & 31;
    float v = (n < OC_) ? w_off[n * KK_ + c * K3_ + tap] : 0.f;
    Bprep[idx] = f2bf(v);
}

// ---------------------------------------------------------------------------
// Offset conv as implicit-GEMM MFMA: D[8000][384] = A[8000][4000]*B[4000][384].
// 2-phase pipeline: global_load_lds direct staging (no VGPR round trip),
// double-buffered LDS (2 x 16KB), ONE barrier per K-step; STAGE(t+1) issued
// before compute(t) so the loads fly under the MFMAs. OOB halo / tap>=125
// lanes redirect their per-lane global source to a 64B zero page.
// Linear 64B LDS rows (required by global_load_lds); fragment reads land on
// 8 uniform 16B bank slots -> conflict-free minimum.
// Tile 64x64, BK=64 (2 taps/iter), 4 waves 2x2, wave tile 32x32,
// mfma 16x16x32 bf16. Writes offbT[v][n] bf16 (+bias).
// ---------------------------------------------------------------------------
__global__ __launch_bounds__(256) void gemm_off_kernel(
    const unsigned short* __restrict__ xtb,
    const unsigned short* __restrict__ Bprep,
    const float* __restrict__ b_off,
    const float* __restrict__ zpage,
    unsigned short* __restrict__ offbT)
{
    __shared__ unsigned short A_lds[2][2][64 * 32];   // [buf][h][row*32+k]
    __shared__ unsigned short B_lds[2][2][64 * 32];

    const int t    = threadIdx.x;
    const int lane = t & 63;
    const int wave = t >> 6;
    const int wr   = wave >> 1;
    const int wc   = wave & 1;
    const int quad = lane >> 4;
    const int lrow = lane & 15;
    const int M0   = blockIdx.x * 64;
    const int N0   = blockIdx.y * 64;

    // Staging geometry: thread t owns (row = t>>2, 16B chunk = t&3).
    // This is exactly wave-uniform-base + lane*16 for global_load_lds:
    // wave w covers rows w*16..w*16+15 (1024B contiguous).
    const int srow = t >> 2;
    const int soff = (t & 3) * 8;           // shorts
    const int mg = M0 + srow;
    const int az = mg / 400, arm = mg % 400;
    const int ay = arm / 20, ax = arm % 20;
    const unsigned short* brow = Bprep + (size_t)(N0 + srow) * KK_;
    const unsigned short* zp   = (const unsigned short*)zpage;
    const int ldsoff = wave * 512;          // shorts: wave's 1024B chunk

    f32x4 acc[2][2] = {};

    auto stage = [&](int buf, int tap0) {
        #pragma unroll
        for (int h = 0; h < 2; ++h) {
            int tap = tap0 + h;                       // uniform -> SALU
            int kz = tap / 25, ky = (tap / 5) % 5, kx = tap % 5;
            int zi = az - 2 + kz, yi = ay - 2 + ky, xi = ax - 2 + kx;
            bool intap = tap < K3_;
            bool ok = intap & ((unsigned)zi < (unsigned)S_)
                            & ((unsigned)yi < (unsigned)S_)
                            & ((unsigned)xi < (unsigned)S_);
            int px = zi * 400 + yi * 20 + xi;
            const unsigned short* ga = ok    ? (xtb + px * 32 + soff)  : zp;
            const unsigned short* gb = intap ? (brow + tap * 32 + soff) : zp;
            __builtin_amdgcn_global_load_lds(
                (const __attribute__((address_space(1))) void*)ga,
                (__attribute__((address_space(3))) void*)(&A_lds[buf][h][ldsoff]),
                16, 0, 0);
            __builtin_amdgcn_global_load_lds(
                (const __attribute__((address_space(1))) void*)gb,
                (__attribute__((address_space(3))) void*)(&B_lds[buf][h][ldsoff]),
                16, 0, 0);
        }
    };

    // Prologue: fill buffer 0, drain, barrier.
    stage(0, 0);
    __syncthreads();

    int cur = 0;
    for (int it = 0; it < 63; ++it) {
        if (it < 62) stage(cur ^ 1, (it + 1) * 2);   // loads fly under compute
        #pragma unroll
        for (int h = 0; h < 2; ++h) {
            bf16x8 af[2], bf[2];
            #pragma unroll
            for (int mi = 0; mi < 2; ++mi)
                af[mi] = *(const bf16x8*)&A_lds[cur][h][(wr * 32 + mi * 16 + lrow) * 32 + quad * 8];
            #pragma unroll
            for (int ni = 0; ni < 2; ++ni)
                bf[ni] = *(const bf16x8*)&B_lds[cur][h][(wc * 32 + ni * 16 + lrow) * 32 + quad * 8];
            #pragma unroll
            for (int mi = 0; mi < 2; ++mi)
                #pragma unroll
                for (int ni = 0; ni < 2; ++ni)
                    acc[mi][ni] = __builtin_amdgcn_mfma_f32_16x16x32_bf16(
                        af[mi], bf[ni], acc[mi][ni], 0, 0, 0);
        }
        __syncthreads();   // waits vmcnt(0): STAGE(t+1) landed; lgkm drained
        cur ^= 1;
    }

    #pragma unroll
    for (int mi = 0; mi < 2; ++mi) {
        #pragma unroll
        for (int ni = 0; ni < 2; ++ni) {
            int n = N0 + wc * 32 + ni * 16 + lrow;
            if (n < OC_) {
                float bias = b_off[n];
                #pragma unroll
                for (int r = 0; r < 4; ++r) {
                    int row = wr * 32 + mi * 16 + quad * 4 + r;
                    offbT[(size_t)(M0 + row) * 384 + n] = f2bf(acc[mi][ni][r] + bias);
                }
            }
        }
    }
}

// ---------------------------------------------------------------------------
// Deformable depthwise sample, two-phase.
// Phase 1: per (voxel, tap) geometry computed ONCE -> 24B in LDS.
// Phase 2: thread=(v,c); 3 broadcast LDS dwords + 8 coalesced gathers + FMAs.
// ---------------------------------------------------------------------------
#define VB 8
__global__ __launch_bounds__(256) void deform_kernel(
    const unsigned short* __restrict__ xtb,
    const float* __restrict__ wdwT,
    const float* __restrict__ b_dw,
    const unsigned short* __restrict__ offbT,
    float* __restrict__ attn1T)
{
    __shared__ unsigned short sw[VB * 128 * 12];   // 24 KB
    const int tid = threadIdx.x;
    const int Vb = blockIdx.x * VB;

    for (int idx = tid; idx < VB * 128; idx += 256) {
        int vl = idx >> 7, tap = idx & 127;
        if (tap < K3_) {
            int v = Vb + vl;
            int z = v / 400, rm = v % 400;
            int y = rm / 20, xx = rm % 20;
            int kz = tap / 25, ky = (tap / 5) % 5, kx = tap % 5;
            const unsigned short* ob = offbT + v * 384 + 3 * tap;
            float pd = (float)(z - 2 + kz) + bf2f(ob[0]);
            float ph = (float)(y - 2 + ky) + bf2f(ob[1]);
            float pw = (float)(xx - 2 + kx) + bf2f(ob[2]);
            float fd0 = floorf(pd), fh0 = floorf(ph), fw0 = floorf(pw);
            float fd = pd - fd0, fh = ph - fh0, fw = pw - fw0;
            int id = (int)fd0, ih = (int)fh0, iw = (int)fw0;
            int d0 = min(max(id, 0), S_ - 1), d1 = min(max(id + 1, 0), S_ - 1);
            int h0 = min(max(ih, 0), S_ - 1), h1 = min(max(ih + 1, 0), S_ - 1);
            int w0 = min(max(iw, 0), S_ - 1), w1 = min(max(iw + 1, 0), S_ - 1);
            float wd0 = ((unsigned)id       < (unsigned)S_) ? 1.f - fd : 0.f;
            float wd1 = ((unsigned)(id + 1) < (unsigned)S_) ? fd       : 0.f;
            float wh0 = ((unsigned)ih       < (unsigned)S_) ? 1.f - fh : 0.f;
            float wh1 = ((unsigned)(ih + 1) < (unsigned)S_) ? fh       : 0.f;
            float ww0 = ((unsigned)iw       < (unsigned)S_) ? 1.f - fw : 0.f;
            float ww1 = ((unsigned)(iw + 1) < (unsigned)S_) ? fw       : 0.f;
            unsigned short* p = &sw[idx * 12];
            p[0] = f2bf(wd0 * wh0); p[1] = f2bf(wd0 * wh1);
            p[2] = f2bf(wd1 * wh0); p[3] = f2bf(wd1 * wh1);
            p[4] = f2bf(ww0);       p[5] = f2bf(ww1);
            p[6] = (unsigned short)(d0 * 400 + h0 * 20);
            p[7] = (unsigned short)(d0 * 400 + h1 * 20);
            p[8] = (unsigned short)(d1 * 400 + h0 * 20);
            p[9] = (unsigned short)(d1 * 400 + h1 * 20);
            p[10] = (unsigned short)w0; p[11] = (unsigned short)w1;
        }
    }
    __syncthreads();

    const int c = tid & 31;
    const int vl = tid >> 5;
    const int v = Vb + vl;
    const unsigned short* xc = xtb + c;
    float acc = 0.f;
    #pragma unroll 2
    for (int tap = 0; tap < K3_; ++tap) {
        const unsigned* pu = (const unsigned*)&sw[(vl * 128 + tap) * 12];
        unsigned u0 = pu[0], u1 = pu[1], u2 = pu[2];
        unsigned u3 = pu[3], u4 = pu[4], u5 = pu[5];
        float wdh00 = asf(u0 << 16), wdh01 = asf(u0 & 0xFFFF0000u);
        float wdh10 = asf(u1 << 16), wdh11 = asf(u1 & 0xFFFF0000u);
        float ww0   = asf(u2 << 16), ww1   = asf(u2 & 0xFFFF0000u);
        int r00 = u3 & 0xFFFFu, r01 = u3 >> 16;
        int r10 = u4 & 0xFFFFu, r11 = u4 >> 16;
        int w0  = u5 & 0xFFFFu, w1  = u5 >> 16;
        float x000 = bf2f(xc[(r00 + w0) * 32]);
        float x001 = bf2f(xc[(r00 + w1) * 32]);
        float x010 = bf2f(xc[(r01 + w0) * 32]);
        float x011 = bf2f(xc[(r01 + w1) * 32]);
        float x100 = bf2f(xc[(r10 + w0) * 32]);
        float x101 = bf2f(xc[(r10 + w1) * 32]);
        float x110 = bf2f(xc[(r11 + w0) * 32]);
        float x111 = bf2f(xc[(r11 + w1) * 32]);
        float s = (x000 * ww0 + x001 * ww1) * wdh00
                + (x010 * ww0 + x011 * ww1) * wdh01
                + (x100 * ww0 + x101 * ww1) * wdh10
                + (x110 * ww0 + x111 * ww1) * wdh11;
        acc += wdwT[tap * 32 + c] * s;
    }
    attn1T[v * 32 + c] = acc + b_dw[c];
}

// ---------------------------------------------------------------------------
// Depthwise 7^3 conv, dilation 3, pad 9, channel-last, coalesced.
// ---------------------------------------------------------------------------
__global__ __launch_bounds__(256) void spatial_kernel(
    const float* __restrict__ wspT,
    const float* __restrict__ b_sp,
    const float* __restrict__ attn1T,
    float* __restrict__ attn2T)
{
    int t = threadIdx.x;
    int c = t & 31;
    int v = blockIdx.x * 8 + (t >> 5);
    int z = v / 400, rm = v % 400;
    int y = rm / 20, xx = rm % 20;

    float acc = 0.f;
    #pragma unroll 1
    for (int kz = 0; kz < 7; ++kz) {
        int zi = z - 9 + 3 * kz;
        bool zv = (unsigned)zi < (unsigned)S_;
        int zc2 = min(max(zi, 0), S_ - 1);
        #pragma unroll 1
        for (int ky = 0; ky < 7; ++ky) {
            int yi = y - 9 + 3 * ky;
            bool yv = (unsigned)yi < (unsigned)S_;
            int yc2 = min(max(yi, 0), S_ - 1);
            int abase = (zc2 * 400 + yc2 * 20) * 32 + c;
            int wbase = (kz * 49 + ky * 7) * 32 + c;
            #pragma unroll
            for (int kx = 0; kx < 7; ++kx) {
                int xi = xx - 9 + 3 * kx;
                bool xv = (unsigned)xi < (unsigned)S_;
                int xc2 = min(max(xi, 0), S_ - 1);
                float a = attn1T[abase + xc2 * 32];
                float w = wspT[wbase + kx * 32];
                acc += (zv && yv && xv) ? a * w : 0.f;
            }
        }
    }
    attn2T[v * 32 + c] = acc + b_sp[c];
}

// ---------------------------------------------------------------------------
// Pointwise 32x32 + bias, gate: out[o][v] = x[o][v] * attn.
// ---------------------------------------------------------------------------
__global__ __launch_bounds__(256) void pw_kernel(
    const float* __restrict__ x,
    const float* __restrict__ wpwT,
    const float* __restrict__ b_pw,
    const float* __restrict__ attn2T,
    float* __restrict__ out)
{
    int t = threadIdx.x;
    int o = t & 31;
    int v = blockIdx.x * 8 + (t >> 5);
    float acc = b_pw[o];
    #pragma unroll
    for (int c = 0; c < C_; ++c)
        acc += wpwT[c * 32 + o] * attn2T[v * 32 + c];
    out[o * V_ + v] = x[o * V_ + v] * acc;
}

// ---------------------------------------------------------------------------
extern "C" void kernel_launch(void* const* d_in, const int* in_sizes, int n_in,
                              void* d_out, int out_size, void* d_ws, size_t ws_size,
                              hipStream_t stream)
{
    const float* x     = (const float*)d_in[0];
    const float* w_off = (const float*)d_in[1];
    const float* b_off = (const float*)d_in[2];
    const float* w_dw  = (const float*)d_in[3];
    const float* b_dw  = (const float*)d_in[4];
    const float* w_sp  = (const float*)d_in[5];
    const float* b_sp  = (const float*)d_in[6];
    const float* w_pw  = (const float*)d_in[7];
    const float* b_pw  = (const float*)d_in[8];
    float* ws = (float*)d_ws;
    float* out = (float*)d_out;

    unsigned short* xtb   = (unsigned short*)(ws + WS_XTB);
    unsigned short* offbT = (unsigned short*)(ws + WS_OFFB);
    unsigned short* Bprep = (unsigned short*)(ws + WS_BPREP);

    hipLaunchKernelGGL(transpose_kernel, dim3((272016 + 255) / 256), dim3(256), 0, stream,
                       x, w_dw, w_sp, w_pw, xtb,
                       ws + WS_WDWT, ws + WS_WSPT, ws + WS_WPWT, ws + WS_ZERO);

    hipLaunchKernelGGL(prep_b_kernel, dim3((NP_ * KK_ + 255) / 256), dim3(256), 0, stream,
                       w_off, Bprep);

    hipLaunchKernelGGL(gemm_off_kernel, dim3(125, 6), dim3(256), 0, stream,
                       xtb, Bprep, b_off, ws + WS_ZERO, offbT);

    hipLaunchKernelGGL(deform_kernel, dim3(1000), dim3(256), 0, stream,
                       xtb, ws + WS_WDWT, b_dw, offbT, ws + WS_ATTN1T);

    hipLaunchKernelGGL(spatial_kernel, dim3(1000), dim3(256), 0, stream,
                       ws + WS_WSPT, b_sp, ws + WS_ATTN1T, ws + WS_ATTN2T);

    hipLaunchKernelGGL(pw_kernel, dim3(1000), dim3(256), 0, stream,
                       x, ws + WS_WPWT, b_pw, ws + WS_ATTN2T, out);
}

// Round 3
// 195.881 us; speedup vs baseline: 1.1496x; 1.1156x over previous
//
#include <hip/hip_runtime.h>
#include <hip/hip_bf16.h>

// Problem constants
#define C_   32
#define S_   20
#define V_   8000     // 20^3
#define K3_  125
#define OC_  375      // 3*K3
#define NP_  384      // padded N
#define KK_  4000     // 32*125

// Workspace layout (float offsets). Peak 2.704M floats = 10.82 MB (unchanged).
#define WS_ATTN1T 0                        // fp32 [v][c]          256000
#define WS_XT     256000                   // f16  [v][c]          128000 fl
#define WS_WDWT   384000                   // fp32 [k][c]            4000
#define WS_WSPT   388000                   // fp32 [k][c]           10976
#define WS_WPWT   398976                   // fp32 [c][o]            1024
#define WS_OFFB   400000                   // f16  [v][384]       1536000 fl
#define WS_BPREP  1936000                  // f16 [n][k] 768000 fl; dead after gemm
#define WS_XP     1936000                  //   -> reused: half2 [v][c] 256000 fl
#define WS_ATTN2T 2192000                  //   -> reused: fp32 [v][c] 256000 fl
// Zero page: first 16 floats of ATTN1T region (dead until deform_kernel).
#define WS_ZERO   WS_ATTN1T

typedef __attribute__((ext_vector_type(8))) short bf16x8;
typedef __attribute__((ext_vector_type(4))) float f32x4;
typedef __fp16 h2_t __attribute__((ext_vector_type(2)));   // matches builtins

static __device__ __forceinline__ unsigned short f2h(float f) {
    _Float16 h = (_Float16)f;
    return __builtin_bit_cast(unsigned short, h);
}
static __device__ __forceinline__ float h2f(unsigned short b) {
    return (float)__builtin_bit_cast(_Float16, b);
}
static __device__ __forceinline__ h2_t bch2(unsigned u) {
    return __builtin_bit_cast(h2_t, u);
}
static __device__ __forceinline__ unsigned pkh2(float a, float b) {
#if __has_builtin(__builtin_amdgcn_cvt_pkrtz)
    return __builtin_bit_cast(unsigned, __builtin_amdgcn_cvt_pkrtz(a, b));
#else
    return (unsigned)f2h(a) | ((unsigned)f2h(b) << 16);
#endif
}
static __device__ __forceinline__ float dot2(unsigned xu, unsigned wu, float c) {
#if __has_builtin(__builtin_amdgcn_fdot2)
    return __builtin_amdgcn_fdot2(bch2(xu), bch2(wu), c, false);
#else
    h2_t xh = bch2(xu), wh = bch2(wu);
    return c + (float)xh[0] * (float)wh[0] + (float)xh[1] * (float)wh[1];
#endif
}

// ---------------------------------------------------------------------------
// Transposes: xt[v][c] f16; wdwT[k][c]; wspT[k][c]; wpwT[c][o] (fp32).
// Also zeroes the 64B zero page used by gemm's OOB lane redirect.
// ---------------------------------------------------------------------------
__global__ __launch_bounds__(256) void transpose_kernel(
    const float* __restrict__ x,
    const float* __restrict__ w_dw,
    const float* __restrict__ w_sp,
    const float* __restrict__ w_pw,
    unsigned short* __restrict__ xt,
    float* __restrict__ wdwT,
    float* __restrict__ wspT,
    float* __restrict__ wpwT,
    float* __restrict__ zpage)
{
    int i = blockIdx.x * 256 + threadIdx.x;
    if (i < 256000) {
        int v = i >> 5, c = i & 31;
        xt[i] = f2h(x[c * V_ + v]);
        return;
    }
    int j = i - 256000;
    if (j < 4000)  { wdwT[j] = w_dw[(j & 31) * K3_ + (j >> 5)]; return; }
    j -= 4000;
    if (j < 10976) { wspT[j] = w_sp[(j & 31) * 343 + (j >> 5)]; return; }
    j -= 10976;
    if (j < 1024)  { wpwT[j] = w_pw[(j & 31) * 32 + (j >> 5)]; return; }
    j -= 1024;
    if (j < 16)    { zpage[j] = 0.f; return; }
}

// ---------------------------------------------------------------------------
// Weight transform: Bprep[n][k] f16, k = tap*32 + c; n >= 375 zeroed.
// ---------------------------------------------------------------------------
__global__ __launch_bounds__(256) void prep_b_kernel(
    const float* __restrict__ w_off, unsigned short* __restrict__ Bprep)
{
    int idx = blockIdx.x * 256 + threadIdx.x;
    if (idx >= NP_ * KK_) return;
    int n = idx / KK_, r = idx % KK_;
    int tap = r >> 5, c = r & 31;
    float v = (n < OC_) ? w_off[n * KK_ + c * K3_ + tap] : 0.f;
    Bprep[idx] = f2h(v);
}

// ---------------------------------------------------------------------------
// Offset conv as implicit-GEMM MFMA (f16): D[8000][384] = A[8000][4000]*B.
// 2-phase pipeline, global_load_lds staging, double-buffered LDS, one
// barrier per K-step. Writes offbT[v][n] f16 (+bias).
// ---------------------------------------------------------------------------
__global__ __launch_bounds__(256) void gemm_off_kernel(
    const unsigned short* __restrict__ xt,
    const unsigned short* __restrict__ Bprep,
    const float* __restrict__ b_off,
    const float* __restrict__ zpage,
    unsigned short* __restrict__ offbT)
{
    __shared__ unsigned short A_lds[2][2][64 * 32];   // [buf][h][row*32+k]
    __shared__ unsigned short B_lds[2][2][64 * 32];

    const int t    = threadIdx.x;
    const int lane = t & 63;
    const int wave = t >> 6;
    const int wr   = wave >> 1;
    const int wc   = wave & 1;
    const int quad = lane >> 4;
    const int lrow = lane & 15;
    const int M0   = blockIdx.x * 64;
    const int N0   = blockIdx.y * 64;

    const int srow = t >> 2;
    const int soff = (t & 3) * 8;           // shorts
    const int mg = M0 + srow;
    const int az = mg / 400, arm = mg % 400;
    const int ay = arm / 20, ax = arm % 20;
    const unsigned short* brow = Bprep + (size_t)(N0 + srow) * KK_;
    const unsigned short* zp   = (const unsigned short*)zpage;
    const int ldsoff = wave * 512;          // shorts: wave's 1024B chunk

    f32x4 acc[2][2] = {};

    auto stage = [&](int buf, int tap0) {
        #pragma unroll
        for (int h = 0; h < 2; ++h) {
            int tap = tap0 + h;
            int kz = tap / 25, ky = (tap / 5) % 5, kx = tap % 5;
            int zi = az - 2 + kz, yi = ay - 2 + ky, xi = ax - 2 + kx;
            bool intap = tap < K3_;
            bool ok = intap & ((unsigned)zi < (unsigned)S_)
                            & ((unsigned)yi < (unsigned)S_)
                            & ((unsigned)xi < (unsigned)S_);
            int px = zi * 400 + yi * 20 + xi;
            const unsigned short* ga = ok    ? (xt + px * 32 + soff)    : zp;
            const unsigned short* gb = intap ? (brow + tap * 32 + soff) : zp;
            __builtin_amdgcn_global_load_lds(
                (const __attribute__((address_space(1))) void*)ga,
                (__attribute__((address_space(3))) void*)(&A_lds[buf][h][ldsoff]),
                16, 0, 0);
            __builtin_amdgcn_global_load_lds(
                (const __attribute__((address_space(1))) void*)gb,
                (__attribute__((address_space(3))) void*)(&B_lds[buf][h][ldsoff]),
                16, 0, 0);
        }
    };

    stage(0, 0);
    __syncthreads();

    int cur = 0;
    for (int it = 0; it < 63; ++it) {
        if (it < 62) stage(cur ^ 1, (it + 1) * 2);
        #pragma unroll
        for (int h = 0; h < 2; ++h) {
            bf16x8 af[2], bf[2];
            #pragma unroll
            for (int mi = 0; mi < 2; ++mi)
                af[mi] = *(const bf16x8*)&A_lds[cur][h][(wr * 32 + mi * 16 + lrow) * 32 + quad * 8];
            #pragma unroll
            for (int ni = 0; ni < 2; ++ni)
                bf[ni] = *(const bf16x8*)&B_lds[cur][h][(wc * 32 + ni * 16 + lrow) * 32 + quad * 8];
            #pragma unroll
            for (int mi = 0; mi < 2; ++mi)
                #pragma unroll
                for (int ni = 0; ni < 2; ++ni)
                    acc[mi][ni] = __builtin_amdgcn_mfma_f32_16x16x32_f16(
                        af[mi], bf[ni], acc[mi][ni], 0, 0, 0);
        }
        __syncthreads();
        cur ^= 1;
    }

    #pragma unroll
    for (int mi = 0; mi < 2; ++mi) {
        #pragma unroll
        for (int ni = 0; ni < 2; ++ni) {
            int n = N0 + wc * 32 + ni * 16 + lrow;
            if (n < OC_) {
                float bias = b_off[n];
                #pragma unroll
                for (int r = 0; r < 4; ++r) {
                    int row = wr * 32 + mi * 16 + quad * 4 + r;
                    offbT[(size_t)(M0 + row) * 384 + n] = f2h(acc[mi][ni][r] + bias);
                }
            }
        }
    }
}

// ---------------------------------------------------------------------------
// xp[v][c] = half2(x[v][c], x[v+1][c]) — makes the (w0,w1) trilinear x-pair
// a single dword load in deform. xp[7999].y = 0 (never used with nonzero wt).
// ---------------------------------------------------------------------------
__global__ __launch_bounds__(256) void pack_xp_kernel(
    const unsigned short* __restrict__ xt, unsigned* __restrict__ xp)
{
    int i = blockIdx.x * 256 + threadIdx.x;
    if (i >= 256000) return;
    unsigned lo = xt[i];
    unsigned hi = (i < 256000 - 32) ? (unsigned)xt[i + 32] : 0u;
    xp[i] = lo | (hi << 16);
}

// ---------------------------------------------------------------------------
// Deformable depthwise sample, two-phase.
// Phase 1: per (voxel, tap) geometry -> 4 packed half2 weights (trilinear
//          factors pre-multiplied) + 4 final gather indices. 32B/entry.
// Phase 2: thread=(v,c); 2 broadcast LDS reads, 4 dword gathers, 4 fdot2.
// ---------------------------------------------------------------------------
#define VB 8
__global__ __launch_bounds__(256) void deform_kernel(
    const unsigned* __restrict__ xp,
    const float* __restrict__ wdwT,
    const float* __restrict__ b_dw,
    const unsigned short* __restrict__ offbT,
    float* __restrict__ attn1T)
{
    __shared__ unsigned sw[VB * 128 * 8];   // 32 KB, 32B per (v,tap) entry
    const int tid = threadIdx.x;
    const int Vb = blockIdx.x * VB;

    for (int idx = tid; idx < VB * 128; idx += 256) {
        int vl = idx >> 7, tap = idx & 127;
        if (tap < K3_) {
            int v = Vb + vl;
            int z = v / 400, rm = v % 400;
            int y = rm / 20, xx = rm % 20;
            int kz = tap / 25, ky = (tap / 5) % 5, kx = tap % 5;
            const unsigned short* ob = offbT + v * 384 + 3 * tap;
            float pd = (float)(z - 2 + kz) + h2f(ob[0]);
            float ph = (float)(y - 2 + ky) + h2f(ob[1]);
            float pw = (float)(xx - 2 + kx) + h2f(ob[2]);
            float fd0 = floorf(pd), fh0 = floorf(ph), fw0 = floorf(pw);
            float fd = pd - fd0, fh = ph - fh0, fw = pw - fw0;
            int id = (int)fd0, ih = (int)fh0, iw = (int)fw0;
            int d0 = min(max(id, 0), S_ - 1), d1 = min(max(id + 1, 0), S_ - 1);
            int h0 = min(max(ih, 0), S_ - 1), h1 = min(max(ih + 1, 0), S_ - 1);
            float wd0 = ((unsigned)id       < (unsigned)S_) ? 1.f - fd : 0.f;
            float wd1 = ((unsigned)(id + 1) < (unsigned)S_) ? fd       : 0.f;
            float wh0 = ((unsigned)ih       < (unsigned)S_) ? 1.f - fh : 0.f;
            float wh1 = ((unsigned)(ih + 1) < (unsigned)S_) ? fh       : 0.f;
            float ww0 = ((unsigned)iw       < (unsigned)S_) ? 1.f - fw : 0.f;
            float ww1 = ((unsigned)(iw + 1) < (unsigned)S_) ? fw       : 0.f;
            // x-pair via xp[p] = (x[p], x[p+1]); iw<0 handled by weight swap.
            int px; float wwa, wwb;
            if (iw < 0) { px = 0;             wwa = ww1; wwb = 0.f; }
            else        { px = min(iw, S_-1); wwa = ww0; wwb = ww1; }
            int r00 = d0 * 400 + h0 * 20 + px;
            int r01 = d0 * 400 + h1 * 20 + px;
            int r10 = d1 * 400 + h0 * 20 + px;
            int r11 = d1 * 400 + h1 * 20 + px;
            float w00 = wd0 * wh0, w01 = wd0 * wh1;
            float w10 = wd1 * wh0, w11 = wd1 * wh1;
            unsigned* q = &sw[idx * 8];
            q[0] = pkh2(w00 * wwa, w00 * wwb);
            q[1] = pkh2(w01 * wwa, w01 * wwb);
            q[2] = pkh2(w10 * wwa, w10 * wwb);
            q[3] = pkh2(w11 * wwa, w11 * wwb);
            q[4] = (unsigned)r00 | ((unsigned)r01 << 16);
            q[5] = (unsigned)r10 | ((unsigned)r11 << 16);
        }
    }
    __syncthreads();

    const int c = tid & 31;
    const int vl = tid >> 5;
    const int v = Vb + vl;
    const unsigned* xpc = xp + c;
    float acc = 0.f;
    #pragma unroll 4
    for (int tap = 0; tap < K3_; ++tap) {
        const unsigned* q = &sw[(vl * 128 + tap) * 8];
        unsigned w00u = q[0], w01u = q[1], w10u = q[2], w11u = q[3];
        unsigned pA = q[4], pB = q[5];
        int p00 = pA & 0xFFFFu, p01 = pA >> 16;
        int p10 = pB & 0xFFFFu, p11 = pB >> 16;
        float s = dot2(xpc[p00 * 32], w00u,
                  dot2(xpc[p01 * 32], w01u,
                  dot2(xpc[p10 * 32], w10u,
                  dot2(xpc[p11 * 32], w11u, 0.f))));
        acc += wdwT[tap * 32 + c] * s;
    }
    attn1T[v * 32 + c] = acc + b_dw[c];
}

// ---------------------------------------------------------------------------
// Depthwise 7^3 conv, dilation 3, pad 9, channel-last, coalesced.
// ---------------------------------------------------------------------------
__global__ __launch_bounds__(256) void spatial_kernel(
    const float* __restrict__ wspT,
    const float* __restrict__ b_sp,
    const float* __restrict__ attn1T,
    float* __restrict__ attn2T)
{
    int t = threadIdx.x;
    int c = t & 31;
    int v = blockIdx.x * 8 + (t >> 5);
    int z = v / 400, rm = v % 400;
    int y = rm / 20, xx = rm % 20;

    float acc = 0.f;
    #pragma unroll 1
    for (int kz = 0; kz < 7; ++kz) {
        int zi = z - 9 + 3 * kz;
        bool zv = (unsigned)zi < (unsigned)S_;
        int zc2 = min(max(zi, 0), S_ - 1);
        #pragma unroll 1
        for (int ky = 0; ky < 7; ++ky) {
            int yi = y - 9 + 3 * ky;
            bool yv = (unsigned)yi < (unsigned)S_;
            int yc2 = min(max(yi, 0), S_ - 1);
            int abase = (zc2 * 400 + yc2 * 20) * 32 + c;
            int wbase = (kz * 49 + ky * 7) * 32 + c;
            #pragma unroll
            for (int kx = 0; kx < 7; ++kx) {
                int xi = xx - 9 + 3 * kx;
                bool xv = (unsigned)xi < (unsigned)S_;
                int xc2 = min(max(xi, 0), S_ - 1);
                float a = attn1T[abase + xc2 * 32];
                float w = wspT[wbase + kx * 32];
                acc += (zv && yv && xv) ? a * w : 0.f;
            }
        }
    }
    attn2T[v * 32 + c] = acc + b_sp[c];
}

// ---------------------------------------------------------------------------
// Pointwise 32x32 + bias, gate: out[o][v] = x[o][v] * attn.
// ---------------------------------------------------------------------------
__global__ __launch_bounds__(256) void pw_kernel(
    const float* __restrict__ x,
    const float* __restrict__ wpwT,
    const float* __restrict__ b_pw,
    const float* __restrict__ attn2T,
    float* __restrict__ out)
{
    int t = threadIdx.x;
    int o = t & 31;
    int v = blockIdx.x * 8 + (t >> 5);
    float acc = b_pw[o];
    #pragma unroll
    for (int c = 0; c < C_; ++c)
        acc += wpwT[c * 32 + o] * attn2T[v * 32 + c];
    out[o * V_ + v] = x[o * V_ + v] * acc;
}

// ---------------------------------------------------------------------------
extern "C" void kernel_launch(void* const* d_in, const int* in_sizes, int n_in,
                              void* d_out, int out_size, void* d_ws, size_t ws_size,
                              hipStream_t stream)
{
    const float* x     = (const float*)d_in[0];
    const float* w_off = (const float*)d_in[1];
    const float* b_off = (const float*)d_in[2];
    const float* w_dw  = (const float*)d_in[3];
    const float* b_dw  = (const float*)d_in[4];
    const float* w_sp  = (const float*)d_in[5];
    const float* b_sp  = (const float*)d_in[6];
    const float* w_pw  = (const float*)d_in[7];
    const float* b_pw  = (const float*)d_in[8];
    float* ws = (float*)d_ws;
    float* out = (float*)d_out;

    unsigned short* xt    = (unsigned short*)(ws + WS_XT);
    unsigned short* offbT = (unsigned short*)(ws + WS_OFFB);
    unsigned short* Bprep = (unsigned short*)(ws + WS_BPREP);
    unsigned*       xp    = (unsigned*)(ws + WS_XP);

    hipLaunchKernelGGL(transpose_kernel, dim3((272016 + 255) / 256), dim3(256), 0, stream,
                       x, w_dw, w_sp, w_pw, xt,
                       ws + WS_WDWT, ws + WS_WSPT, ws + WS_WPWT, ws + WS_ZERO);

    hipLaunchKernelGGL(prep_b_kernel, dim3((NP_ * KK_ + 255) / 256), dim3(256), 0, stream,
                       w_off, Bprep);

    hipLaunchKernelGGL(gemm_off_kernel, dim3(125, 6), dim3(256), 0, stream,
                       xt, Bprep, b_off, ws + WS_ZERO, offbT);

    hipLaunchKernelGGL(pack_xp_kernel, dim3(1000), dim3(256), 0, stream,
                       xt, xp);

    hipLaunchKernelGGL(deform_kernel, dim3(1000), dim3(256), 0, stream,
                       xp, ws + WS_WDWT, b_dw, offbT, ws + WS_ATTN1T);

    hipLaunchKernelGGL(spatial_kernel, dim3(1000), dim3(256), 0, stream,
                       ws + WS_WSPT, b_sp, ws + WS_ATTN1T, ws + WS_ATTN2T);

    hipLaunchKernelGGL(pw_kernel, dim3(1000), dim3(256), 0, stream,
                       x, ws + WS_WPWT, b_pw, ws + WS_ATTN2T, out);
}

// Round 4
// 193.027 us; speedup vs baseline: 1.1666x; 1.0148x over previous
//
#include <hip/hip_runtime.h>
#include <hip/hip_bf16.h>

// Problem constants
#define C_   32
#define S_   20
#define V_   8000     // 20^3
#define K3_  125
#define OC_  375      // 3*K3
#define NP_  384      // padded N
#define KK_  4000     // 32*125

// Workspace layout (float offsets). Peak 2.704M floats = 10.82 MB (unchanged).
#define WS_ATTN1T 0                        // fp32 [v][c]          256000
#define WS_XT     256000                   // f16  [v][c]          128000 fl
#define WS_WDWT   384000                   // fp32 [k][c]            4000
#define WS_WSPT   388000                   // fp32 [k][c]           10976
#define WS_WPWT   398976                   // fp32 [c][o]            1024
#define WS_OFFB   400000                   // f16  [v][384]       1536000 fl
#define WS_BPREP  1936000                  // f16 [n][k] 768000 fl; dead after gemm
#define WS_XP     1936000                  //   -> reused: half2 [v][c] 256000 fl
#define WS_ATTN2T 2192000                  //   -> reused: fp32 [v][c] 256000 fl
// Zero page: first 16 floats of ATTN1T region (dead until deform_kernel).
#define WS_ZERO   WS_ATTN1T

typedef __attribute__((ext_vector_type(8))) short bf16x8;
typedef __attribute__((ext_vector_type(4))) float f32x4;
typedef __fp16 h2_t __attribute__((ext_vector_type(2)));   // matches builtins

static __device__ __forceinline__ unsigned short f2h(float f) {
    _Float16 h = (_Float16)f;
    return __builtin_bit_cast(unsigned short, h);
}
static __device__ __forceinline__ float h2f(unsigned short b) {
    return (float)__builtin_bit_cast(_Float16, b);
}
static __device__ __forceinline__ h2_t bch2(unsigned u) {
    return __builtin_bit_cast(h2_t, u);
}
static __device__ __forceinline__ unsigned pkh2(float a, float b) {
#if __has_builtin(__builtin_amdgcn_cvt_pkrtz)
    return __builtin_bit_cast(unsigned, __builtin_amdgcn_cvt_pkrtz(a, b));
#else
    return (unsigned)f2h(a) | ((unsigned)f2h(b) << 16);
#endif
}
static __device__ __forceinline__ float dot2(unsigned xu, unsigned wu, float c) {
#if __has_builtin(__builtin_amdgcn_fdot2)
    return __builtin_amdgcn_fdot2(bch2(xu), bch2(wu), c, false);
#else
    h2_t xh = bch2(xu), wh = bch2(wu);
    return c + (float)xh[0] * (float)wh[0] + (float)xh[1] * (float)wh[1];
#endif
}

// ---------------------------------------------------------------------------
// Transposes: xt[v][c] f16; wdwT[k][c]; wspT[k][c]; wpwT[c][o] (fp32).
// Also zeroes the 64B zero page used by gemm's OOB lane redirect.
// ---------------------------------------------------------------------------
__global__ __launch_bounds__(256) void transpose_kernel(
    const float* __restrict__ x,
    const float* __restrict__ w_dw,
    const float* __restrict__ w_sp,
    const float* __restrict__ w_pw,
    unsigned short* __restrict__ xt,
    float* __restrict__ wdwT,
    float* __restrict__ wspT,
    float* __restrict__ wpwT,
    float* __restrict__ zpage)
{
    int i = blockIdx.x * 256 + threadIdx.x;
    if (i < 256000) {
        int v = i >> 5, c = i & 31;
        xt[i] = f2h(x[c * V_ + v]);
        return;
    }
    int j = i - 256000;
    if (j < 4000)  { wdwT[j] = w_dw[(j & 31) * K3_ + (j >> 5)]; return; }
    j -= 4000;
    if (j < 10976) { wspT[j] = w_sp[(j & 31) * 343 + (j >> 5)]; return; }
    j -= 10976;
    if (j < 1024)  { wpwT[j] = w_pw[(j & 31) * 32 + (j >> 5)]; return; }
    j -= 1024;
    if (j < 16)    { zpage[j] = 0.f; return; }
}

// ---------------------------------------------------------------------------
// Weight transform: Bprep[n][k] f16, k = tap*32 + c; n >= 375 zeroed.
// ---------------------------------------------------------------------------
__global__ __launch_bounds__(256) void prep_b_kernel(
    const float* __restrict__ w_off, unsigned short* __restrict__ Bprep)
{
    int idx = blockIdx.x * 256 + threadIdx.x;
    if (idx >= NP_ * KK_) return;
    int n = idx / KK_, r = idx % KK_;
    int tap = r >> 5, c = r & 31;
    float v = (n < OC_) ? w_off[n * KK_ + c * K3_ + tap] : 0.f;
    Bprep[idx] = f2h(v);
}

// ---------------------------------------------------------------------------
// Offset conv as implicit-GEMM MFMA (f16): D[8000][384] = A[8000][4000]*B.
// 2-phase pipeline, global_load_lds staging, double-buffered LDS, one
// barrier per K-step.
// LDS XOR-swizzle (T2, rule #21 both-sides): phys = logical ^
// (((logical>>7)&3)<<4). Write side keeps the linear global_load_lds dest
// and inverse-swizzles the per-lane GLOBAL chunk; read side XORs the quad.
// Kills the (lrow&1,quad) 2x bank serialization on ds_read_b128.
// Writes offbT[v][n] f16 (+bias).
// ---------------------------------------------------------------------------
__global__ __launch_bounds__(256) void gemm_off_kernel(
    const unsigned short* __restrict__ xt,
    const unsigned short* __restrict__ Bprep,
    const float* __restrict__ b_off,
    const float* __restrict__ zpage,
    unsigned short* __restrict__ offbT)
{
    __shared__ unsigned short A_lds[2][2][64 * 32];   // [buf][h][row*32+k]
    __shared__ unsigned short B_lds[2][2][64 * 32];

    const int t    = threadIdx.x;
    const int lane = t & 63;
    const int wave = t >> 6;
    const int wr   = wave >> 1;
    const int wc   = wave & 1;
    const int quad = lane >> 4;
    const int lrow = lane & 15;
    const int M0   = blockIdx.x * 64;
    const int N0   = blockIdx.y * 64;

    // Staging: thread t's phys LDS dest is t*16 B (linear, hardware-imposed).
    // Inverse-swizzled logical chunk it must fetch: (t&3) ^ ((t>>3)&3).
    const int srow = t >> 2;
    const int soff = ((t & 3) ^ ((t >> 3) & 3)) * 8;   // shorts, swizzled
    const int mg = M0 + srow;
    const int az = mg / 400, arm = mg % 400;
    const int ay = arm / 20, ax = arm % 20;
    const unsigned short* brow = Bprep + (size_t)(N0 + srow) * KK_;
    const unsigned short* zp   = (const unsigned short*)zpage;
    const int ldsoff = wave * 512;          // shorts: wave's 1024B chunk
    // Read-side swizzle constant (mi/ni/wr/wc add multiples of 8 to row>>1).
    const int xorc = (lrow >> 1) & 3;

    f32x4 acc[2][2] = {};

    auto stage = [&](int buf, int tap0) {
        #pragma unroll
        for (int h = 0; h < 2; ++h) {
            int tap = tap0 + h;
            int kz = tap / 25, ky = (tap / 5) % 5, kx = tap % 5;
            int zi = az - 2 + kz, yi = ay - 2 + ky, xi = ax - 2 + kx;
            bool intap = tap < K3_;
            bool ok = intap & ((unsigned)zi < (unsigned)S_)
                            & ((unsigned)yi < (unsigned)S_)
                            & ((unsigned)xi < (unsigned)S_);
            int px = zi * 400 + yi * 20 + xi;
            const unsigned short* ga = ok    ? (xt + px * 32 + soff)    : zp;
            const unsigned short* gb = intap ? (brow + tap * 32 + soff) : zp;
            __builtin_amdgcn_global_load_lds(
                (const __attribute__((address_space(1))) void*)ga,
                (__attribute__((address_space(3))) void*)(&A_lds[buf][h][ldsoff]),
                16, 0, 0);
            __builtin_amdgcn_global_load_lds(
                (const __attribute__((address_space(1))) void*)gb,
                (__attribute__((address_space(3))) void*)(&B_lds[buf][h][ldsoff]),
                16, 0, 0);
        }
    };

    stage(0, 0);
    __syncthreads();

    int cur = 0;
    for (int it = 0; it < 63; ++it) {
        if (it < 62) stage(cur ^ 1, (it + 1) * 2);
        #pragma unroll
        for (int h = 0; h < 2; ++h) {
            bf16x8 af[2], bf[2];
            #pragma unroll
            for (int mi = 0; mi < 2; ++mi)
                af[mi] = *(const bf16x8*)&A_lds[cur][h][(wr * 32 + mi * 16 + lrow) * 32 + (quad ^ xorc) * 8];
            #pragma unroll
            for (int ni = 0; ni < 2; ++ni)
                bf[ni] = *(const bf16x8*)&B_lds[cur][h][(wc * 32 + ni * 16 + lrow) * 32 + (quad ^ xorc) * 8];
            #pragma unroll
            for (int mi = 0; mi < 2; ++mi)
                #pragma unroll
                for (int ni = 0; ni < 2; ++ni)
                    acc[mi][ni] = __builtin_amdgcn_mfma_f32_16x16x32_f16(
                        af[mi], bf[ni], acc[mi][ni], 0, 0, 0);
        }
        __syncthreads();
        cur ^= 1;
    }

    #pragma unroll
    for (int mi = 0; mi < 2; ++mi) {
        #pragma unroll
        for (int ni = 0; ni < 2; ++ni) {
            int n = N0 + wc * 32 + ni * 16 + lrow;
            if (n < OC_) {
                float bias = b_off[n];
                #pragma unroll
                for (int r = 0; r < 4; ++r) {
                    int row = wr * 32 + mi * 16 + quad * 4 + r;
                    offbT[(size_t)(M0 + row) * 384 + n] = f2h(acc[mi][ni][r] + bias);
                }
            }
        }
    }
}

// ---------------------------------------------------------------------------
// xp[v][c] = half2(x[v][c], x[v+1][c]) — makes the (w0,w1) trilinear x-pair
// a single dword load in deform. xp[7999].y = 0 (never used with nonzero wt).
// ---------------------------------------------------------------------------
__global__ __launch_bounds__(256) void pack_xp_kernel(
    const unsigned short* __restrict__ xt, unsigned* __restrict__ xp)
{
    int i = blockIdx.x * 256 + threadIdx.x;
    if (i >= 256000) return;
    unsigned lo = xt[i];
    unsigned hi = (i < 256000 - 32) ? (unsigned)xt[i + 32] : 0u;
    xp[i] = lo | (hi << 16);
}

// ---------------------------------------------------------------------------
// Deformable depthwise sample, two-phase.
// Phase 1: per (voxel, tap) geometry -> 4 packed half2 weights (trilinear
//          factors pre-multiplied) + 4 final gather indices. 32B/entry.
// Phase 2: thread=(v,c); 2 broadcast LDS reads, 4 dword gathers, 4 fdot2.
// ---------------------------------------------------------------------------
#define VB 8
__global__ __launch_bounds__(256) void deform_kernel(
    const unsigned* __restrict__ xp,
    const float* __restrict__ wdwT,
    const float* __restrict__ b_dw,
    const unsigned short* __restrict__ offbT,
    float* __restrict__ attn1T)
{
    __shared__ unsigned sw[VB * 128 * 8];   // 32 KB, 32B per (v,tap) entry
    const int tid = threadIdx.x;
    const int Vb = blockIdx.x * VB;

    for (int idx = tid; idx < VB * 128; idx += 256) {
        int vl = idx >> 7, tap = idx & 127;
        if (tap < K3_) {
            int v = Vb + vl;
            int z = v / 400, rm = v % 400;
            int y = rm / 20, xx = rm % 20;
            int kz = tap / 25, ky = (tap / 5) % 5, kx = tap % 5;
            const unsigned short* ob = offbT + v * 384 + 3 * tap;
            float pd = (float)(z - 2 + kz) + h2f(ob[0]);
            float ph = (float)(y - 2 + ky) + h2f(ob[1]);
            float pw = (float)(xx - 2 + kx) + h2f(ob[2]);
            float fd0 = floorf(pd), fh0 = floorf(ph), fw0 = floorf(pw);
            float fd = pd - fd0, fh = ph - fh0, fw = pw - fw0;
            int id = (int)fd0, ih = (int)fh0, iw = (int)fw0;
            int d0 = min(max(id, 0), S_ - 1), d1 = min(max(id + 1, 0), S_ - 1);
            int h0 = min(max(ih, 0), S_ - 1), h1 = min(max(ih + 1, 0), S_ - 1);
            float wd0 = ((unsigned)id       < (unsigned)S_) ? 1.f - fd : 0.f;
            float wd1 = ((unsigned)(id + 1) < (unsigned)S_) ? fd       : 0.f;
            float wh0 = ((unsigned)ih       < (unsigned)S_) ? 1.f - fh : 0.f;
            float wh1 = ((unsigned)(ih + 1) < (unsigned)S_) ? fh       : 0.f;
            float ww0 = ((unsigned)iw       < (unsigned)S_) ? 1.f - fw : 0.f;
            float ww1 = ((unsigned)(iw + 1) < (unsigned)S_) ? fw       : 0.f;
            // x-pair via xp[p] = (x[p], x[p+1]); iw<0 handled by weight swap.
            int px; float wwa, wwb;
            if (iw < 0) { px = 0;             wwa = ww1; wwb = 0.f; }
            else        { px = min(iw, S_-1); wwa = ww0; wwb = ww1; }
            int r00 = d0 * 400 + h0 * 20 + px;
            int r01 = d0 * 400 + h1 * 20 + px;
            int r10 = d1 * 400 + h0 * 20 + px;
            int r11 = d1 * 400 + h1 * 20 + px;
            float w00 = wd0 * wh0, w01 = wd0 * wh1;
            float w10 = wd1 * wh0, w11 = wd1 * wh1;
            unsigned* q = &sw[idx * 8];
            q[0] = pkh2(w00 * wwa, w00 * wwb);
            q[1] = pkh2(w01 * wwa, w01 * wwb);
            q[2] = pkh2(w10 * wwa, w10 * wwb);
            q[3] = pkh2(w11 * wwa, w11 * wwb);
            q[4] = (unsigned)r00 | ((unsigned)r01 << 16);
            q[5] = (unsigned)r10 | ((unsigned)r11 << 16);
        }
    }
    __syncthreads();

    const int c = tid & 31;
    const int vl = tid >> 5;
    const int v = Vb + vl;
    const unsigned* xpc = xp + c;
    float acc = 0.f;
    #pragma unroll 4
    for (int tap = 0; tap < K3_; ++tap) {
        const unsigned* q = &sw[(vl * 128 + tap) * 8];
        unsigned w00u = q[0], w01u = q[1], w10u = q[2], w11u = q[3];
        unsigned pA = q[4], pB = q[5];
        int p00 = pA & 0xFFFFu, p01 = pA >> 16;
        int p10 = pB & 0xFFFFu, p11 = pB >> 16;
        float s = dot2(xpc[p00 * 32], w00u,
                  dot2(xpc[p01 * 32], w01u,
                  dot2(xpc[p10 * 32], w10u,
                  dot2(xpc[p11 * 32], w11u, 0.f))));
        acc += wdwT[tap * 32 + c] * s;
    }
    attn1T[v * 32 + c] = acc + b_dw[c];
}

// ---------------------------------------------------------------------------
// Depthwise 7^3 conv, dilation 3, pad 9, channel-last, coalesced.
// ---------------------------------------------------------------------------
__global__ __launch_bounds__(256) void spatial_kernel(
    const float* __restrict__ wspT,
    const float* __restrict__ b_sp,
    const float* __restrict__ attn1T,
    float* __restrict__ attn2T)
{
    int t = threadIdx.x;
    int c = t & 31;
    int v = blockIdx.x * 8 + (t >> 5);
    int z = v / 400, rm = v % 400;
    int y = rm / 20, xx = rm % 20;

    float acc = 0.f;
    #pragma unroll 1
    for (int kz = 0; kz < 7; ++kz) {
        int zi = z - 9 + 3 * kz;
        bool zv = (unsigned)zi < (unsigned)S_;
        int zc2 = min(max(zi, 0), S_ - 1);
        #pragma unroll 1
        for (int ky = 0; ky < 7; ++ky) {
            int yi = y - 9 + 3 * ky;
            bool yv = (unsigned)yi < (unsigned)S_;
            int yc2 = min(max(yi, 0), S_ - 1);
            int abase = (zc2 * 400 + yc2 * 20) * 32 + c;
            int wbase = (kz * 49 + ky * 7) * 32 + c;
            #pragma unroll
            for (int kx = 0; kx < 7; ++kx) {
                int xi = xx - 9 + 3 * kx;
                bool xv = (unsigned)xi < (unsigned)S_;
                int xc2 = min(max(xi, 0), S_ - 1);
                float a = attn1T[abase + xc2 * 32];
                float w = wspT[wbase + kx * 32];
                acc += (zv && yv && xv) ? a * w : 0.f;
            }
        }
    }
    attn2T[v * 32 + c] = acc + b_sp[c];
}

// ---------------------------------------------------------------------------
// Pointwise 32x32 + bias, gate: out[o][v] = x[o][v] * attn.
// ---------------------------------------------------------------------------
__global__ __launch_bounds__(256) void pw_kernel(
    const float* __restrict__ x,
    const float* __restrict__ wpwT,
    const float* __restrict__ b_pw,
    const float* __restrict__ attn2T,
    float* __restrict__ out)
{
    int t = threadIdx.x;
    int o = t & 31;
    int v = blockIdx.x * 8 + (t >> 5);
    float acc = b_pw[o];
    #pragma unroll
    for (int c = 0; c < C_; ++c)
        acc += wpwT[c * 32 + o] * attn2T[v * 32 + c];
    out[o * V_ + v] = x[o * V_ + v] * acc;
}

// ---------------------------------------------------------------------------
extern "C" void kernel_launch(void* const* d_in, const int* in_sizes, int n_in,
                              void* d_out, int out_size, void* d_ws, size_t ws_size,
                              hipStream_t stream)
{
    const float* x     = (const float*)d_in[0];
    const float* w_off = (const float*)d_in[1];
    const float* b_off = (const float*)d_in[2];
    const float* w_dw  = (const float*)d_in[3];
    const float* b_dw  = (const float*)d_in[4];
    const float* w_sp  = (const float*)d_in[5];
    const float* b_sp  = (const float*)d_in[6];
    const float* w_pw  = (const float*)d_in[7];
    const float* b_pw  = (const float*)d_in[8];
    float* ws = (float*)d_ws;
    float* out = (float*)d_out;

    unsigned short* xt    = (unsigned short*)(ws + WS_XT);
    unsigned short* offbT = (unsigned short*)(ws + WS_OFFB);
    unsigned short* Bprep = (unsigned short*)(ws + WS_BPREP);
    unsigned*       xp    = (unsigned*)(ws + WS_XP);

    hipLaunchKernelGGL(transpose_kernel, dim3((272016 + 255) / 256), dim3(256), 0, stream,
                       x, w_dw, w_sp, w_pw, xt,
                       ws + WS_WDWT, ws + WS_WSPT, ws + WS_WPWT, ws + WS_ZERO);

    hipLaunchKernelGGL(prep_b_kernel, dim3((NP_ * KK_ + 255) / 256), dim3(256), 0, stream,
                       w_off, Bprep);

    hipLaunchKernelGGL(gemm_off_kernel, dim3(125, 6), dim3(256), 0, stream,
                       xt, Bprep, b_off, ws + WS_ZERO, offbT);

    hipLaunchKernelGGL(pack_xp_kernel, dim3(1000), dim3(256), 0, stream,
                       xt, xp);

    hipLaunchKernelGGL(deform_kernel, dim3(1000), dim3(256), 0, stream,
                       xp, ws + WS_WDWT, b_dw, offbT, ws + WS_ATTN1T);

    hipLaunchKernelGGL(spatial_kernel, dim3(1000), dim3(256), 0, stream,
                       ws + WS_WSPT, b_sp, ws + WS_ATTN1T, ws + WS_ATTN2T);

    hipLaunchKernelGGL(pw_kernel, dim3(1000), dim3(256), 0, stream,
                       x, ws + WS_WPWT, b_pw, ws + WS_ATTN2T, out);
}